// Round 9
// baseline (642.174 us; speedup 1.0000x reference)
//
#include <hip/hip_runtime.h>
#include <hip/hip_bf16.h>

// Shapes: B=2, C=256, H=W=24 (HW=576), G=16, Cg=16, GRID=25, AC=6400, Mg=400
// Inputs fp32, output fp32.
// ws layout (fp32): h1f[16*2*256*576] | pooled[16*2*6400] | aff[16*2*16]
// Fixed per-iter harness cost: d_ws poison fill ~43 us. Only kernel time counts.

typedef __attribute__((ext_vector_type(8))) short short8;
typedef __attribute__((ext_vector_type(4))) float f32x4;

static __device__ __forceinline__ short f2bf(float x) {
    unsigned u = __float_as_uint(x);
    unsigned r = (u + 0x7fffu + ((u >> 16) & 1u)) >> 16;   // RNE
    return (short)r;
}

// LDS byte-offset map (phase overlay):
//  phase1: xs [row27][col26][ci p24] @0 (33696) | wA [kk5][co16][k p40] @33696 (6400)
//  phase2: hsb [s576][j p20] @0 (23040) | wlb [m400][j16] @23040 (12800)
//          bias2 [m400] @35840 (1600) | psum [w8][m400] @37440 (12800)
//  zpad 16B @50240 (zeros for masked-lane MFMA frag reads)
#define WA_OFF  33696
#define WLB_OFF 23040
#define B2_OFF  35840
#define PS_OFF  37440
#define ZP_OFF  50240
#define SMEM_BYTES 50256

__global__ __launch_bounds__(512, 4) void k12_fused(
    const float* __restrict__ xin,
    const float* __restrict__ W1,
    const float* __restrict__ g1, const float* __restrict__ b1,
    const float* __restrict__ m1, const float* __restrict__ v1,
    const float* __restrict__ W2,
    const float* __restrict__ g2, const float* __restrict__ b2,
    const float* __restrict__ m2, const float* __restrict__ v2,
    float* __restrict__ h1f,
    float* __restrict__ pooled)
{
    __shared__ __align__(16) char smem[SMEM_BYTES];
    short* xs    = (short*)smem;
    short* wAp   = (short*)(smem + WA_OFF);
    short* hsb   = (short*)smem;
    short* wlb   = (short*)(smem + WLB_OFF);
    float* bias2 = (float*)(smem + B2_OFF);
    float* psum  = (float*)(smem + PS_OFF);
    __shared__ float scale1[16], bias1[16];

    int bid = blockIdx.x;                      // i*32 + b*16 + g
    int i = bid >> 5, b = (bid >> 4) & 1, g = bid & 15;
    int t = threadIdx.x;

    // ---- phase 1 staging: zero pad regions, fold BN1 ----
    int* xz = (int*)xs;
    for (int idx = t; idx < 27*26*12; idx += 512) xz[idx] = 0;
    if (t < 4) ((int*)(smem + ZP_OFF))[t] = 0;
    if (t < 16) {
        int c = i*256 + g*16 + t;
        float sc = g1[c] * rsqrtf(v1[c] + 1e-5f);
        scale1[t] = sc;
        bias1[t]  = b1[c] - m1[c] * sc;
    }
    __syncthreads();

    const float* xb = &xin[(b*256 + g*16)*576];
    for (int idx = t; idx < 9216; idx += 512) {
        int ci = idx / 576; int s = idx - ci*576;
        int y = s / 24; int x = s - y*24;
        xs[((y+1)*26 + (x+1))*24 + ci] = f2bf(xb[idx]);
    }
    const float* wb = &W1[(i*256 + g*16)*144];    // [co][ci][9]
    for (int idx = t; idx < 2560; idx += 512) {
        int kk = idx >> 9, rem = idx & 511, co = rem >> 5, k = rem & 31;
        int tap = 2*kk + (k >> 4), ci = k & 15;
        float val = (tap < 9) ? wb[co*144 + ci*9 + tap] * scale1[co] : 0.f;
        wAp[(kk*16 + co)*40 + k] = f2bf(val);
    }
    __syncthreads();

    int l = t & 63, w = t >> 6;                // 8 waves
    int quad = l >> 4, rc = l & 15;

    // ---- phase 1 compute: tiles tt = w, w+8, ... (4-5 per wave), 5 MFMA each ----
    f32x4 dreg[5];
    {
        int ci0 = (quad & 1) * 8;
        short8 afr[5];
#pragma unroll
        for (int kk = 0; kk < 5; kk++)
            afr[kk] = *(const short8*)&wAp[(kk*16 + rc)*40 + quad*8];
        f32x4 cb1 = *(const f32x4*)&bias1[quad*4];

        const int offE[5] = {0, 48, 648, 1248, 1296};     // taps 0,2,4,6,8
        const int offO[5] = {24, 624, 672, 1272, 1872};   // taps 1,3,5,7,9
        int off[5];
#pragma unroll
        for (int kk = 0; kk < 5; kk++) off[kk] = (quad >= 2) ? offO[kk] : offE[kk];

        int n = 0;
        for (int tt = w; tt < 36; tt += 8, ++n) {
            int s = tt*16 + rc;
            int y = s / 24; int x = s - y*24;
            int base = (y*26 + x)*24 + ci0;
            f32x4 acc = cb1;
#pragma unroll
            for (int kk = 0; kk < 5; kk++) {
                short8 bf = *(const short8*)&xs[base + off[kk]];
                acc = __builtin_amdgcn_mfma_f32_16x16x32_bf16(afr[kk], bf, acc, 0, 0, 0);
            }
#pragma unroll
            for (int r = 0; r < 4; r++) acc[r] = fmaxf(acc[r], 0.f);
            dreg[n] = acc;
        }
    }
    __syncthreads();   // all xs/wA reads done; safe to overlay hsb/wlb/bias2

    // write h to LDS (bf16, [s][j] pitch 20) and to global fp32 for k4
    {
        float* hout = &h1f[((i*2 + b)*256 + g*16)*576];
        int n = 0;
        for (int tt = w; tt < 36; tt += 8, ++n) {
            int s = tt*16 + rc;
            f32x4 acc = dreg[n];
            unsigned p0 = (unsigned)(unsigned short)f2bf(acc[0]) |
                          ((unsigned)(unsigned short)f2bf(acc[1]) << 16);
            unsigned p1 = (unsigned)(unsigned short)f2bf(acc[2]) |
                          ((unsigned)(unsigned short)f2bf(acc[3]) << 16);
            uint2 pk = {p0, p1};
            *(uint2*)&hsb[s*20 + quad*4] = pk;
#pragma unroll
            for (int r = 0; r < 4; r++)
                hout[(quad*4 + r)*576 + s] = acc[r];
        }
    }

    // ---- phase 2 staging: W2*s2 -> wlb, bias2 ----
    for (int m = t; m < 400; m += 512) {
        int o = i*6400 + g*400 + m;
        float s2 = g2[o] * rsqrtf(v2[o] + 1e-5f);
        bias2[m] = b2[o] - m2[o] * s2;
        const float4* wr = (const float4*)&W2[o*16];
#pragma unroll
        for (int q = 0; q < 4; q++) {
            float4 wv = wr[q];
            wlb[m*16 + q*4 + 0] = f2bf(wv.x * s2);
            wlb[m*16 + q*4 + 1] = f2bf(wv.y * s2);
            wlb[m*16 + q*4 + 2] = f2bf(wv.z * s2);
            wlb[m*16 + q*4 + 3] = f2bf(wv.w * s2);
        }
    }
    __syncthreads();

    // ---- phase 2: D2[s,m] = h(s,j) * W2'(j,m) + be[m]; per-lane row-sum of
    // relu; A-frags = this wave's own h tiles, registered (loaded once) ----
    {
        int q8 = (quad & 1) * 8;               // j-offset for quads 0/1; 2/3 read zpad
        short8 af2[5];
        int ntile = 0;
        for (int tt = w; tt < 36; tt += 8, ++ntile) {
            int boff = (l < 32) ? (((tt*16 + rc)*20 + q8)*2) : ZP_OFF;
            af2[ntile] = *(const short8*)(smem + boff);
        }
        for (int mt = 0; mt < 25; mt++) {
            int m0 = mt*16;
            int woff = (l < 32) ? (WLB_OFF + ((m0 + rc)*16 + q8)*2) : ZP_OFF;
            short8 wf = *(const short8*)(smem + woff);
            float be = bias2[m0 + rc];
            f32x4 cb = {be, be, be, be};       // bias per column m

            f32x4 accv = {0.f, 0.f, 0.f, 0.f};
            for (int n = 0; n < ntile; n++) {
                f32x4 d = __builtin_amdgcn_mfma_f32_16x16x32_bf16(af2[n], wf, cb, 0, 0, 0);
#pragma unroll
                for (int r = 0; r < 4; r++)
                    accv[r] += fmaxf(d[r], 0.f);
            }
            float a = (accv[0] + accv[1]) + (accv[2] + accv[3]);
            a += __shfl_xor(a, 16);            // sum 4 quads = 16 rows per tile
            a += __shfl_xor(a, 32);
            if (l < 16)
                psum[w*400 + m0 + l] = a;      // partial over this wave's s-set
        }
    }
    __syncthreads();

    const float inv = 1.f / 676.f;             // 26x26 pool incl. 100 border px
    for (int m = t; m < 400; m += 512) {
        float s = 0.f;
#pragma unroll
        for (int ww = 0; ww < 8; ww++) s += psum[ww*400 + m];
        float be = bias2[m];
        pooled[(i*2+b)*6400 + g*400 + m] = (s + 100.f * fmaxf(be, 0.f)) * inv;
    }
}

__global__ __launch_bounds__(256) void k3_aff(const float* __restrict__ pooled,
                                              float* __restrict__ aff)
{
    __shared__ float th[400];
    __shared__ float parts[256];
    int bid = blockIdx.x;           // i*2 + b
    int i = bid >> 1;
    int t = threadIdx.x;
    const float* pb = &pooled[bid*6400];
    for (int idx = t; idx < 400; idx += 256) th[idx] = pb[i*400 + idx];
    __syncthreads();
    int l = t >> 4, p = t & 15;
    float sum = 0.f;
    const float* pl = &pb[l*400];
    for (int m = p*25; m < p*25 + 25; m++) sum = fmaf(th[m], pl[m], sum);
    parts[t] = sum;
    __syncthreads();
    if (t < 16) {
        float s = 0.f;
        for (int pp = 0; pp < 16; pp++) s += parts[t*16 + pp];
        aff[bid*16 + t] = s * (1.f/16.f);
    }
}

__global__ __launch_bounds__(256) void k4_out(const float* __restrict__ h1f,
                                              const float* __restrict__ aff,
                                              float* __restrict__ out)
{
    __shared__ float a0[16], a1[16];
    int bid = blockIdx.x;           // i*32 + q*16 + cg
    int i = bid >> 5, q = (bid >> 4) & 1, cg = bid & 15;
    int t = threadIdx.x;
    if (t < 16) a0[t] = aff[(i*2+0)*16 + t];
    else if (t < 32) a1[t-16] = aff[(i*2+1)*16 + (t-16)];
    __syncthreads();
    const float* hb = &h1f[((i*2+q)*256 + cg)*576];
    int ch = i*32 + q*16 + cg;
    for (int s = t; s < 576; s += 256) {
        float acc0 = 0.f, acc1 = 0.f;
#pragma unroll
        for (int k = 0; k < 16; k++) {
            float v = hb[k*9216 + s];
            acc0 = fmaf(a0[k], v, acc0);
            acc1 = fmaf(a1[k], v, acc1);
        }
        out[ch*576 + s]         = acc0;
        out[(512 + ch)*576 + s] = acc1;
    }
}

extern "C" void kernel_launch(void* const* d_in, const int* in_sizes, int n_in,
                              void* d_out, int out_size, void* d_ws, size_t ws_size,
                              hipStream_t stream)
{
    const float* x  = (const float*)d_in[0];
    const float* W1 = (const float*)d_in[1];
    const float* g1 = (const float*)d_in[2];
    const float* b1 = (const float*)d_in[3];
    const float* m1 = (const float*)d_in[4];
    const float* v1 = (const float*)d_in[5];
    const float* W2 = (const float*)d_in[6];
    const float* g2 = (const float*)d_in[7];
    const float* b2 = (const float*)d_in[8];
    const float* m2 = (const float*)d_in[9];
    const float* v2 = (const float*)d_in[10];

    float* h1f    = (float*)d_ws;
    float* pooled = h1f + 16*2*256*576;     // +4,718,592 floats
    float* aff    = pooled + 16*2*6400;     // +204,800 floats

    float* out = (float*)d_out;

    hipLaunchKernelGGL(k12_fused, dim3(512), dim3(512), 0, stream,
                       x, W1, g1, b1, m1, v1, W2, g2, b2, m2, v2, h1f, pooled);
    hipLaunchKernelGGL(k3_aff,    dim3(32),  dim3(256), 0, stream,
                       pooled, aff);
    hipLaunchKernelGGL(k4_out,    dim3(512), dim3(256), 0, stream,
                       h1f, aff, out);
}

// Round 10
// 117.461 us; speedup vs baseline: 5.4671x; 5.4671x over previous
//
#include <hip/hip_runtime.h>
#include <hip/hip_bf16.h>

// Shapes: B=2, C=256, H=W=24 (HW=576), G=16, Cg=16, GRID=25, AC=6400, Mg=400
// Inputs fp32, output fp32.
// ws layout (fp32): h1f[16*2*256*576] | pooled[16*2*6400] | aff[16*2*16]
// Fixed per-iter harness cost: d_ws poison fill ~43 us. Only kernel time counts.
// LESSON (R9): per-lane arrays (dreg/af2/afr) must be indexed ONLY by
// compile-time constants from fully-unrolled loops — runtime indexing
// spills to scratch (VGPR 40, 12x regression).

typedef __attribute__((ext_vector_type(8))) short short8;
typedef __attribute__((ext_vector_type(4))) short short4v;
typedef __attribute__((ext_vector_type(4))) float f32x4;

static __device__ __forceinline__ short f2bf(float x) {
    unsigned u = __float_as_uint(x);
    unsigned r = (u + 0x7fffu + ((u >> 16) & 1u)) >> 16;   // RNE
    return (short)r;
}

// LDS byte-offset map (phase overlay):
//  phase1: xs [row27][col26][ci p24] @0 (33696) | wA [kk5][co16][k p40] @33696 (6400)
//  phase2: hsb [s576][j p20] @0 (23040) | wlb [m400][j16] @23040 (12800)
//          bias2 [m400] @35840 (1600) | psum [w4][m400] @37440 (6400)
//  zpad 16B @43840 (zeros for masked-lane MFMA frag reads; above both phases)
#define WA_OFF  33696
#define WLB_OFF 23040
#define B2_OFF  35840
#define PS_OFF  37440
#define ZP_OFF  43840
#define SMEM_BYTES 43856

__global__ __launch_bounds__(256) void k12_fused(
    const float* __restrict__ xin,
    const float* __restrict__ W1,
    const float* __restrict__ g1, const float* __restrict__ b1,
    const float* __restrict__ m1, const float* __restrict__ v1,
    const float* __restrict__ W2,
    const float* __restrict__ g2, const float* __restrict__ b2,
    const float* __restrict__ m2, const float* __restrict__ v2,
    float* __restrict__ h1f,
    float* __restrict__ pooled)
{
    __shared__ __align__(16) char smem[SMEM_BYTES];
    short* xs    = (short*)smem;
    short* wAp   = (short*)(smem + WA_OFF);
    short* hsb   = (short*)smem;
    short* wlb   = (short*)(smem + WLB_OFF);
    float* bias2 = (float*)(smem + B2_OFF);
    float* psum  = (float*)(smem + PS_OFF);
    __shared__ float scale1[16], bias1[16];

    int bid = blockIdx.x;                      // i*32 + b*16 + g
    int i = bid >> 5, b = (bid >> 4) & 1, g = bid & 15;
    int t = threadIdx.x;

    // ---- phase 1 staging: zero pad regions, fold BN1 ----
    int* xz = (int*)xs;
    for (int idx = t; idx < 27*26*12; idx += 256) xz[idx] = 0;
    if (t < 4) ((int*)(smem + ZP_OFF))[t] = 0;
    if (t < 16) {
        int c = i*256 + g*16 + t;
        float sc = g1[c] * rsqrtf(v1[c] + 1e-5f);
        scale1[t] = sc;
        bias1[t]  = b1[c] - m1[c] * sc;
    }
    __syncthreads();

    const float* xb = &xin[(b*256 + g*16)*576];
    for (int idx = t; idx < 9216; idx += 256) {
        int ci = idx / 576; int s = idx - ci*576;
        int y = s / 24; int x = s - y*24;
        xs[((y+1)*26 + (x+1))*24 + ci] = f2bf(xb[idx]);
    }
    const float* wb = &W1[(i*256 + g*16)*144];    // [co][ci][9]
    for (int idx = t; idx < 2560; idx += 256) {
        int kk = idx >> 9, rem = idx & 511, co = rem >> 5, k = rem & 31;
        int tap = 2*kk + (k >> 4), ci = k & 15;
        float val = (tap < 9) ? wb[co*144 + ci*9 + tap] * scale1[co] : 0.f;
        wAp[(kk*16 + co)*40 + k] = f2bf(val);
    }
    __syncthreads();

    int l = t & 63, w = t >> 6;                // 4 waves, 9 pixel-tiles each
    int quad = l >> 4, rc = l & 15;

    // ---- phase 1 compute: D(16co x 576px) = W1'(16x144)*im2col + bias1 ----
    f32x4 dreg[9];
    {
        int ci0 = (quad & 1) * 8;
        short8 afr[5];
#pragma unroll
        for (int kk = 0; kk < 5; kk++)
            afr[kk] = *(const short8*)&wAp[(kk*16 + rc)*40 + quad*8];
        f32x4 cb1 = *(const f32x4*)&bias1[quad*4];

        const int offE[5] = {0, 48, 648, 1248, 1296};     // taps 0,2,4,6,8
        const int offO[5] = {24, 624, 672, 1272, 1872};   // taps 1,3,5,7,9
        int off[5];
#pragma unroll
        for (int kk = 0; kk < 5; kk++) off[kk] = (quad >= 2) ? offO[kk] : offE[kk];

#pragma unroll
        for (int tt = 0; tt < 9; tt++) {
            int s = (w*9 + tt)*16 + rc;
            int y = s / 24; int x = s - y*24;
            int base = (y*26 + x)*24 + ci0;
            f32x4 acc = cb1;
#pragma unroll
            for (int kk = 0; kk < 5; kk++) {
                short8 bf = *(const short8*)&xs[base + off[kk]];
                acc = __builtin_amdgcn_mfma_f32_16x16x32_bf16(afr[kk], bf, acc, 0, 0, 0);
            }
#pragma unroll
            for (int r = 0; r < 4; r++) acc[r] = fmaxf(acc[r], 0.f);
            dreg[tt] = acc;
        }
    }
    __syncthreads();   // all xs/wA reads done; safe to overlay hsb/wlb/bias2

    // write h to LDS (bf16, [s][j] pitch 20) and to global fp32 for k4
    {
        float* hout = &h1f[((i*2 + b)*256 + g*16)*576];
#pragma unroll
        for (int tt = 0; tt < 9; tt++) {
            int s = (w*9 + tt)*16 + rc;
            f32x4 acc = dreg[tt];
            unsigned p0 = (unsigned)(unsigned short)f2bf(acc[0]) |
                          ((unsigned)(unsigned short)f2bf(acc[1]) << 16);
            unsigned p1 = (unsigned)(unsigned short)f2bf(acc[2]) |
                          ((unsigned)(unsigned short)f2bf(acc[3]) << 16);
            uint2 pk = {p0, p1};
            *(uint2*)&hsb[s*20 + quad*4] = pk;
#pragma unroll
            for (int r = 0; r < 4; r++)
                hout[(quad*4 + r)*576 + s] = acc[r];
        }
    }

    // ---- phase 2 staging: W2*s2 -> wlb, bias2 ----
    for (int m = t; m < 400; m += 256) {
        int o = i*6400 + g*400 + m;
        float s2 = g2[o] * rsqrtf(v2[o] + 1e-5f);
        bias2[m] = b2[o] - m2[o] * s2;
        const float4* wr = (const float4*)&W2[o*16];
#pragma unroll
        for (int q = 0; q < 4; q++) {
            float4 wv = wr[q];
            wlb[m*16 + q*4 + 0] = f2bf(wv.x * s2);
            wlb[m*16 + q*4 + 1] = f2bf(wv.y * s2);
            wlb[m*16 + q*4 + 2] = f2bf(wv.z * s2);
            wlb[m*16 + q*4 + 3] = f2bf(wv.w * s2);
        }
    }
    __syncthreads();

    // ---- phase 2 (transposed, registered A): D2[s,m] = h(s,j)*W2'(j,m)+be[m].
    // A-frags = this wave's own 9 h-tiles, loaded once; B = W2 strip per mt.
    // Pool = per-lane row-sum of relu + 2 shfl (quads) -> psum[w][m]. ----
    {
        int q8 = (quad & 1) * 8;               // j-offset quads 0/1; 2/3 read zpad
        short8 af2[9];
#pragma unroll
        for (int u = 0; u < 9; u++) {
            int boff = (l < 32) ? ((((w*9 + u)*16 + rc)*20 + q8)*2) : ZP_OFF;
            af2[u] = *(const short8*)(smem + boff);
        }
        for (int mt = 0; mt < 25; mt++) {
            int m0 = mt*16;
            int woff = (l < 32) ? (WLB_OFF + ((m0 + rc)*16 + q8)*2) : ZP_OFF;
            short8 wf = *(const short8*)(smem + woff);
            float be = bias2[m0 + rc];
            f32x4 cb = {be, be, be, be};       // bias per column m

            f32x4 accv = {0.f, 0.f, 0.f, 0.f};
#pragma unroll
            for (int u = 0; u < 9; u++) {
                f32x4 d = __builtin_amdgcn_mfma_f32_16x16x32_bf16(af2[u], wf, cb, 0, 0, 0);
#pragma unroll
                for (int r = 0; r < 4; r++)
                    accv[r] += fmaxf(d[r], 0.f);
            }
            float a = (accv[0] + accv[1]) + (accv[2] + accv[3]);
            a += __shfl_xor(a, 16);            // sum 4 quads = 16 rows per tile
            a += __shfl_xor(a, 32);
            if (l < 16)
                psum[w*400 + m0 + l] = a;      // partial over this wave's 144 px
        }
    }
    __syncthreads();

    const float inv = 1.f / 676.f;             // 26x26 pool incl. 100 border px
    for (int m = t; m < 400; m += 256) {
        float s = psum[0*400+m] + psum[1*400+m] + psum[2*400+m] + psum[3*400+m];
        float be = bias2[m];
        pooled[(i*2+b)*6400 + g*400 + m] = (s + 100.f * fmaxf(be, 0.f)) * inv;
    }
}

__global__ __launch_bounds__(256) void k3_aff(const float* __restrict__ pooled,
                                              float* __restrict__ aff)
{
    __shared__ float th[400];
    __shared__ float parts[256];
    int bid = blockIdx.x;           // i*2 + b
    int i = bid >> 1;
    int t = threadIdx.x;
    const float* pb = &pooled[bid*6400];
    for (int idx = t; idx < 400; idx += 256) th[idx] = pb[i*400 + idx];
    __syncthreads();
    int l = t >> 4, p = t & 15;
    float sum = 0.f;
    const float* pl = &pb[l*400];
    for (int m = p*25; m < p*25 + 25; m++) sum = fmaf(th[m], pl[m], sum);
    parts[t] = sum;
    __syncthreads();
    if (t < 16) {
        float s = 0.f;
        for (int pp = 0; pp < 16; pp++) s += parts[t*16 + pp];
        aff[bid*16 + t] = s * (1.f/16.f);
    }
}

__global__ __launch_bounds__(256) void k4_out(const float* __restrict__ h1f,
                                              const float* __restrict__ aff,
                                              float* __restrict__ out)
{
    __shared__ float a0[16], a1[16];
    int bid = blockIdx.x;           // i*32 + q*16 + cg
    int i = bid >> 5, q = (bid >> 4) & 1, cg = bid & 15;
    int t = threadIdx.x;
    if (t < 16) a0[t] = aff[(i*2+0)*16 + t];
    else if (t < 32) a1[t-16] = aff[(i*2+1)*16 + (t-16)];
    __syncthreads();
    const float* hb = &h1f[((i*2+q)*256 + cg)*576];
    int ch = i*32 + q*16 + cg;
    for (int s = t; s < 576; s += 256) {
        float acc0 = 0.f, acc1 = 0.f;
#pragma unroll
        for (int k = 0; k < 16; k++) {
            float v = hb[k*9216 + s];
            acc0 = fmaf(a0[k], v, acc0);
            acc1 = fmaf(a1[k], v, acc1);
        }
        out[ch*576 + s]         = acc0;
        out[(512 + ch)*576 + s] = acc1;
    }
}

extern "C" void kernel_launch(void* const* d_in, const int* in_sizes, int n_in,
                              void* d_out, int out_size, void* d_ws, size_t ws_size,
                              hipStream_t stream)
{
    const float* x  = (const float*)d_in[0];
    const float* W1 = (const float*)d_in[1];
    const float* g1 = (const float*)d_in[2];
    const float* b1 = (const float*)d_in[3];
    const float* m1 = (const float*)d_in[4];
    const float* v1 = (const float*)d_in[5];
    const float* W2 = (const float*)d_in[6];
    const float* g2 = (const float*)d_in[7];
    const float* b2 = (const float*)d_in[8];
    const float* m2 = (const float*)d_in[9];
    const float* v2 = (const float*)d_in[10];

    float* h1f    = (float*)d_ws;
    float* pooled = h1f + 16*2*256*576;     // +4,718,592 floats
    float* aff    = pooled + 16*2*6400;     // +204,800 floats

    float* out = (float*)d_out;

    hipLaunchKernelGGL(k12_fused, dim3(512), dim3(256), 0, stream,
                       x, W1, g1, b1, m1, v1, W2, g2, b2, m2, v2, h1f, pooled);
    hipLaunchKernelGGL(k3_aff,    dim3(32),  dim3(256), 0, stream,
                       pooled, aff);
    hipLaunchKernelGGL(k4_out,    dim3(512), dim3(256), 0, stream,
                       h1f, aff, out);
}